// Round 1
// baseline (850.421 us; speedup 1.0000x reference)
//
#include <hip/hip_runtime.h>
#include <stdint.h>

#define H_DIM 256
#define NCOL 8192
#define TOPK 512
#define CAND_CAP 8192

// monotonic float -> uint key (order-preserving for all finite floats)
__device__ __forceinline__ unsigned fkey(float f) {
  unsigned u = __float_as_uint(f);
  unsigned m = (unsigned)((int)u >> 31) | 0x80000000u;
  return u ^ m;
}

__global__ __launch_bounds__(256) void zero_ws(unsigned* __restrict__ ghist,
                                               unsigned* __restrict__ counter) {
  int t = blockIdx.x * blockDim.x + threadIdx.x;
  if (t < 4096) ghist[t] = 0;
  if (t == 0) *counter = 0;
}

// ---------------- MLP layer: Y[rows,256] = act(X[rows,K] @ W[K,256] + b) ----------------
// block = 16 rows x 256 cols(threads)
template <int K, bool RELU>
__global__ __launch_bounds__(256) void mlp_layer(const float* __restrict__ X,
                                                 const float* __restrict__ W,
                                                 const float* __restrict__ bias,
                                                 float* __restrict__ Y) {
  __shared__ float Xs[16 * K];
  const int t = threadIdx.x;
  const int row0 = blockIdx.x * 16;
  for (int f = t; f < 4 * K; f += 256) {  // 16*K/4 float4s
    *(float4*)(Xs + f * 4) = *(const float4*)(X + row0 * K + f * 4);
  }
  __syncthreads();
  float acc[16];
#pragma unroll
  for (int r = 0; r < 16; r++) acc[r] = 0.f;
  for (int d = 0; d < K; d += 4) {
    float w0 = W[(d + 0) * H_DIM + t];
    float w1 = W[(d + 1) * H_DIM + t];
    float w2 = W[(d + 2) * H_DIM + t];
    float w3 = W[(d + 3) * H_DIM + t];
#pragma unroll
    for (int r = 0; r < 16; r++) {
      float4 x = *(const float4*)(Xs + r * K + d);
      acc[r] = fmaf(x.x, w0, acc[r]);
      acc[r] = fmaf(x.y, w1, acc[r]);
      acc[r] = fmaf(x.z, w2, acc[r]);
      acc[r] = fmaf(x.w, w3, acc[r]);
    }
  }
  const float bv = bias[t];
#pragma unroll
  for (int r = 0; r < 16; r++) {
    float v = acc[r] + bv;
    if (RELU) v = fmaxf(v, 0.f);
    Y[(row0 + r) * H_DIM + t] = v;
  }
}

// ---------------- big GEMM: C[8192,8192] = A[8192,256] * B[8192,256]^T, fused histogram ----------------
// block tile 128(M) x 256(N), 256 threads, 8x16 per thread, K chunks of 32
__global__ __launch_bounds__(256, 2) void gemm_sim(const float* __restrict__ A,
                                                   const float* __restrict__ B,
                                                   float* __restrict__ C,
                                                   unsigned* __restrict__ ghist) {
  __shared__ float As[32 * 128];   // [k][row] 16KB
  __shared__ float Bs[32 * 256];   // [k][col] 32KB
  __shared__ unsigned hist[4096];  // 16KB  (total 64KB)
  const int t = threadIdx.x;
  const int tx = t & 15, ty = t >> 4;
  const int m0 = blockIdx.y * 128, n0 = blockIdx.x * 256;
  for (int i = t; i < 4096; i += 256) hist[i] = 0;
  float acc[8][16];
#pragma unroll
  for (int i = 0; i < 8; i++)
#pragma unroll
    for (int j = 0; j < 16; j++) acc[i][j] = 0.f;

  for (int kc = 0; kc < H_DIM; kc += 32) {
    __syncthreads();
    // stage A: 128 rows x 32 k, coalesced float4 global reads, transpose into [k][row]
#pragma unroll
    for (int i = 0; i < 4; i++) {
      int v = t + i * 256;
      int r = v >> 3, k4 = v & 7;
      float4 a4 = *(const float4*)(A + (m0 + r) * H_DIM + kc + k4 * 4);
      As[(k4 * 4 + 0) * 128 + r] = a4.x;
      As[(k4 * 4 + 1) * 128 + r] = a4.y;
      As[(k4 * 4 + 2) * 128 + r] = a4.z;
      As[(k4 * 4 + 3) * 128 + r] = a4.w;
    }
    // stage B: 256 rows x 32 k
#pragma unroll
    for (int i = 0; i < 8; i++) {
      int v = t + i * 256;
      int r = v >> 3, k4 = v & 7;
      float4 b4 = *(const float4*)(B + (n0 + r) * H_DIM + kc + k4 * 4);
      Bs[(k4 * 4 + 0) * 256 + r] = b4.x;
      Bs[(k4 * 4 + 1) * 256 + r] = b4.y;
      Bs[(k4 * 4 + 2) * 256 + r] = b4.z;
      Bs[(k4 * 4 + 3) * 256 + r] = b4.w;
    }
    __syncthreads();
#pragma unroll 2
    for (int kk = 0; kk < 32; kk++) {
      float a[8], b[16];
      *(float4*)&a[0] = *(const float4*)(As + kk * 128 + ty * 8);
      *(float4*)&a[4] = *(const float4*)(As + kk * 128 + ty * 8 + 4);
#pragma unroll
      for (int m = 0; m < 4; m++)
        *(float4*)&b[m * 4] = *(const float4*)(Bs + kk * 256 + tx * 4 + m * 64);
#pragma unroll
      for (int i = 0; i < 8; i++)
#pragma unroll
        for (int j = 0; j < 16; j++) acc[i][j] = fmaf(a[i], b[j], acc[i][j]);
    }
  }
  // epilogue: coalesced float4 stores + LDS histogram of every value
#pragma unroll
  for (int i = 0; i < 8; i++) {
    size_t row = (size_t)(m0 + ty * 8 + i);
#pragma unroll
    for (int m = 0; m < 4; m++) {
      float4 v;
      v.x = acc[i][m * 4 + 0];
      v.y = acc[i][m * 4 + 1];
      v.z = acc[i][m * 4 + 2];
      v.w = acc[i][m * 4 + 3];
      *(float4*)(C + row * NCOL + n0 + tx * 4 + m * 64) = v;
      atomicAdd(&hist[fkey(v.x) >> 20], 1u);
      atomicAdd(&hist[fkey(v.y) >> 20], 1u);
      atomicAdd(&hist[fkey(v.z) >> 20], 1u);
      atomicAdd(&hist[fkey(v.w) >> 20], 1u);
    }
  }
  __syncthreads();
  for (int b = t; b < 4096; b += 256) {
    unsigned c = hist[b];
    if (c) atomicAdd(&ghist[b], c);
  }
}

// ---------------- threshold: smallest bin b* s.t. count(key >= b*<<20) >= TOPK ----------------
__global__ __launch_bounds__(256) void find_thresh(const unsigned* __restrict__ ghist,
                                                   unsigned* __restrict__ thresh) {
  __shared__ unsigned part[256];
  const int t = threadIdx.x;
  unsigned s = 0;
#pragma unroll
  for (int b = 0; b < 16; b++) s += ghist[t * 16 + b];
  part[t] = s;
  __syncthreads();
  if (t == 0) {
    unsigned cum = 0;
    int g = 255;
    for (; g > 0; g--) {
      if (cum + part[g] >= TOPK) break;
      cum += part[g];
    }
    int bsel = g * 16;
    for (int b = g * 16 + 15; b >= g * 16; b--) {
      cum += ghist[b];
      if (cum >= TOPK) { bsel = b; break; }
    }
    *thresh = (unsigned)bsel << 20;
  }
}

// ---------------- collect all candidates >= threshold ----------------
__global__ __launch_bounds__(256) void collect(const float* __restrict__ sim,
                                               const unsigned* __restrict__ thresh,
                                               unsigned long long* __restrict__ cand,
                                               unsigned* __restrict__ counter) {
  const unsigned thr = *thresh;
  const int stride = gridDim.x * blockDim.x;
  const int total4 = (NCOL * NCOL) / 4;  // 16,777,216
  const float4* s4 = (const float4*)sim;
  for (int i = blockIdx.x * blockDim.x + threadIdx.x; i < total4; i += stride) {
    float4 v = s4[i];
    unsigned base = (unsigned)i * 4u;
    unsigned k;
    k = fkey(v.x);
    if (k >= thr) {
      unsigned p = atomicAdd(counter, 1u);
      if (p < CAND_CAP) cand[p] = ((unsigned long long)k << 32) | (unsigned long long)(0xFFFFFFFFu - (base + 0u));
    }
    k = fkey(v.y);
    if (k >= thr) {
      unsigned p = atomicAdd(counter, 1u);
      if (p < CAND_CAP) cand[p] = ((unsigned long long)k << 32) | (unsigned long long)(0xFFFFFFFFu - (base + 1u));
    }
    k = fkey(v.z);
    if (k >= thr) {
      unsigned p = atomicAdd(counter, 1u);
      if (p < CAND_CAP) cand[p] = ((unsigned long long)k << 32) | (unsigned long long)(0xFFFFFFFFu - (base + 2u));
    }
    k = fkey(v.w);
    if (k >= thr) {
      unsigned p = atomicAdd(counter, 1u);
      if (p < CAND_CAP) cand[p] = ((unsigned long long)k << 32) | (unsigned long long)(0xFFFFFFFFu - (base + 3u));
    }
  }
}

// ---------------- single-block bitonic sort of candidates, write top-512 (row,col) as floats ----------------
__global__ __launch_bounds__(1024) void sort_topk(const unsigned long long* __restrict__ cand,
                                                  const unsigned* __restrict__ counter,
                                                  float* __restrict__ out) {
  __shared__ unsigned long long s[CAND_CAP];  // 64KB
  const int t = threadIdx.x;
  int n = (int)min(*counter, (unsigned)CAND_CAP);
  int P = 512;
  while (P < n) P <<= 1;  // <= CAND_CAP
  for (int i = t; i < P; i += 1024) s[i] = (i < n) ? cand[i] : 0ULL;
  __syncthreads();
  for (int k = 2; k <= P; k <<= 1) {
    for (int j = k >> 1; j > 0; j >>= 1) {
      for (int i = t; i < P; i += 1024) {
        int l = i ^ j;
        if (l > i) {
          bool desc = ((i & k) == 0);
          unsigned long long a = s[i], b = s[l];
          bool sw = desc ? (a < b) : (a > b);
          if (sw) { s[i] = b; s[l] = a; }
        }
      }
      __syncthreads();
    }
  }
  if (t < TOPK) {
    unsigned long long c = s[t];
    unsigned idx = 0xFFFFFFFFu - (unsigned)(c & 0xFFFFFFFFull);
    unsigned row = idx >> 13;        // /8192
    unsigned col = idx & 8191u;      // %8192
    out[t * 2 + 0] = (float)row;
    out[t * 2 + 1] = (float)col;
  }
}

extern "C" void kernel_launch(void* const* d_in, const int* in_sizes, int n_in,
                              void* d_out, int out_size, void* d_ws, size_t ws_size,
                              hipStream_t stream) {
  const float* desc0 = (const float*)d_in[0];
  const float* desc1 = (const float*)d_in[1];
  const float* W0a = (const float*)d_in[2];
  const float* b0a = (const float*)d_in[3];
  const float* W0b = (const float*)d_in[4];
  const float* b0b = (const float*)d_in[5];
  const float* W1a = (const float*)d_in[6];
  const float* b1a = (const float*)d_in[7];
  const float* W1b = (const float*)d_in[8];
  const float* b1b = (const float*)d_in[9];

  char* ws = (char*)d_ws;
  unsigned* ghist = (unsigned*)ws;                                  // 16KB
  unsigned* counter = (unsigned*)(ws + 16384);                     // 4B
  unsigned* thresh = (unsigned*)(ws + 16388);                      // 4B
  unsigned long long* cand = (unsigned long long*)(ws + 16448);    // 64KB
  float* mdesc0 = (float*)(ws + 131072);                           // 8MB
  float* mdesc1 = mdesc0 + 8192 * 256;                             // 8MB
  float* hbuf = mdesc1 + 8192 * 256;                               // 8MB

  float* outf = (float*)d_out;
  float* sim = outf + TOPK * 2;  // sim at float offset 1024 (16B aligned)

  zero_ws<<<16, 256, 0, stream>>>(ghist, counter);

  mlp_layer<128, true><<<512, 256, 0, stream>>>(desc0, W0a, b0a, hbuf);
  mlp_layer<256, false><<<512, 256, 0, stream>>>(hbuf, W0b, b0b, mdesc0);
  mlp_layer<128, true><<<512, 256, 0, stream>>>(desc1, W1a, b1a, hbuf);
  mlp_layer<256, false><<<512, 256, 0, stream>>>(hbuf, W1b, b1b, mdesc1);

  gemm_sim<<<dim3(32, 64), 256, 0, stream>>>(mdesc0, mdesc1, sim, ghist);
  find_thresh<<<1, 256, 0, stream>>>(ghist, thresh);
  collect<<<4096, 256, 0, stream>>>(sim, thresh, cand, counter);
  sort_topk<<<1, 1024, 0, stream>>>(cand, counter, outf);
}